// Round 1
// baseline (10530.758 us; speedup 1.0000x reference)
//
#include <hip/hip_runtime.h>
#include <hip/hip_bf16.h>
#include <cmath>

// Problem dims (fixed)
#define B_ 64
#define L_ 197
#define D_ 768
#define H_ 12
#define NL_ 12
#define F_ 3072
#define M_ (B_*L_)      // 12608 = 197*64 -> divisible by 64

typedef __bf16 bf16_t;
typedef __bf16 bf16x8 __attribute__((ext_vector_type(8)));
typedef __bf16 bf16x4 __attribute__((ext_vector_type(4)));
typedef float  f32x4  __attribute__((ext_vector_type(4)));

__device__ __forceinline__ float gelu_f(float x) {
    return 0.5f * x * (1.f + erff(x * 0.70710678118654752440f));
}

// ---------------- elementwise: h = x + pos (fp32, float4) ----------------
__global__ __launch_bounds__(256) void k_addpos4(const float4* __restrict__ x,
                                                 const float4* __restrict__ pos,
                                                 float4* __restrict__ h,
                                                 int n4, int ld4) {
    int i = blockIdx.x * 256 + threadIdx.x;
    if (i < n4) {
        float4 a = x[i];
        float4 p = pos[i % ld4];
        float4 r; r.x = a.x + p.x; r.y = a.y + p.y; r.z = a.z + p.z; r.w = a.w + p.w;
        h[i] = r;
    }
}

// ---------------- weight fp32 -> bf16 (float4 granularity) ----------------
__global__ __launch_bounds__(256) void k_conv4(const float* __restrict__ in,
                                               bf16_t* __restrict__ out, int n4) {
    int i = blockIdx.x * 256 + threadIdx.x;
    if (i < n4) {
        float4 v = ((const float4*)in)[i];
        bf16x4 o;
        o[0] = (bf16_t)v.x; o[1] = (bf16_t)v.y; o[2] = (bf16_t)v.z; o[3] = (bf16_t)v.w;
        ((bf16x4*)out)[i] = o;
    }
}

// pack Wq|Wk|Wv -> wqkv[768][2304] bf16
__global__ __launch_bounds__(256) void k_pack_qkvw(const float* __restrict__ wq,
                                                   const float* __restrict__ wk,
                                                   const float* __restrict__ wv,
                                                   bf16_t* __restrict__ wqkv) {
    int i = blockIdx.x * 256 + threadIdx.x;      // over 768*768/4
    if (i >= D_*D_/4) return;
    int k = i / (D_/4), j4 = i % (D_/4);
    const float* srcs[3] = {wq, wk, wv};
    #pragma unroll
    for (int sel = 0; sel < 3; ++sel) {
        float4 v = ((const float4*)srcs[sel])[i];
        bf16x4 o;
        o[0] = (bf16_t)v.x; o[1] = (bf16_t)v.y; o[2] = (bf16_t)v.z; o[3] = (bf16_t)v.w;
        ((bf16x4*)(wqkv + (size_t)k*2304 + sel*D_))[j4] = o;
    }
}

__global__ __launch_bounds__(256) void k_pack_qkvb(const float* __restrict__ bq,
                                                   const float* __restrict__ bk,
                                                   const float* __restrict__ bv,
                                                   float* __restrict__ bqkv) {
    int i = blockIdx.x * 256 + threadIdx.x;
    if (i < D_) { bqkv[i] = bq[i]; bqkv[D_ + i] = bk[i]; bqkv[2*D_ + i] = bv[i]; }
}

// ---------------- LayerNorm: one wave per row (D=768 = 64 lanes * 12) ----------------
template<bool BF16OUT>
__global__ __launch_bounds__(256) void k_ln(const float* __restrict__ x,
                                            const float* __restrict__ g,
                                            const float* __restrict__ bsh,
                                            void* __restrict__ out) {
    int wid = threadIdx.x >> 6, lane = threadIdx.x & 63;
    size_t row = (size_t)blockIdx.x * 4 + wid;
    const float4* xr = (const float4*)(x + row * D_);
    float4 v[3];
    float s = 0.f, sq = 0.f;
    #pragma unroll
    for (int i = 0; i < 3; ++i) {
        v[i] = xr[i*64 + lane];
        s  += v[i].x + v[i].y + v[i].z + v[i].w;
        sq += v[i].x*v[i].x + v[i].y*v[i].y + v[i].z*v[i].z + v[i].w*v[i].w;
    }
    #pragma unroll
    for (int o = 1; o < 64; o <<= 1) { s += __shfl_xor(s, o); sq += __shfl_xor(sq, o); }
    float mean = s * (1.f/768.f);
    float var  = sq * (1.f/768.f) - mean*mean;
    float rstd = rsqrtf(var + 1e-6f);
    const float4* g4 = (const float4*)g;
    const float4* b4 = (const float4*)bsh;
    #pragma unroll
    for (int i = 0; i < 3; ++i) {
        float4 gg = g4[i*64 + lane], bb = b4[i*64 + lane];
        float4 r;
        r.x = (v[i].x - mean)*rstd*gg.x + bb.x;
        r.y = (v[i].y - mean)*rstd*gg.y + bb.y;
        r.z = (v[i].z - mean)*rstd*gg.z + bb.z;
        r.w = (v[i].w - mean)*rstd*gg.w + bb.w;
        if (BF16OUT) {
            bf16x4 o4; o4[0]=(bf16_t)r.x; o4[1]=(bf16_t)r.y; o4[2]=(bf16_t)r.z; o4[3]=(bf16_t)r.w;
            ((bf16x4*)((bf16_t*)out + row * D_))[i*64 + lane] = o4;
        } else {
            ((float4*)out)[row * (D_/4) + i*64 + lane] = r;
        }
    }
}

// ---------------- GEMM: C[M,N] = A[M,K](bf16) * Bw[K,N](bf16) + bias ----------------
// Tile 64x64, BK=32, 4 waves (2x2), each wave 32x32 via 2x2 mfma_f32_16x16x32_bf16.
// EPI: 0 = bias -> bf16 ; 1 = bias+gelu -> bf16 ; 2 = bias+resid(f32) -> f32
template<int EPI>
__global__ __launch_bounds__(256) void k_gemm(const bf16_t* __restrict__ A,
                                              const bf16_t* __restrict__ Bw,
                                              const float* __restrict__ bias,
                                              const float* __restrict__ resid,
                                              void* __restrict__ Cout,
                                              int K, int N) {
    __shared__ bf16_t As[64][48];   // row stride 96B (16B-aligned)
    __shared__ bf16_t Bs[64][48];   // transposed: Bs[n][k]
    int tid = threadIdx.x;
    int lane = tid & 63, wid = tid >> 6;
    int gm0 = blockIdx.x * 64, gn0 = blockIdx.y * 64;
    int wr = (wid >> 1) * 32, wc = (wid & 1) * 32;

    f32x4 zero = {0.f, 0.f, 0.f, 0.f};
    f32x4 acc[2][2];
    acc[0][0] = zero; acc[0][1] = zero; acc[1][0] = zero; acc[1][1] = zero;

    int arow = tid >> 2, acg = (tid & 3) * 8;   // A stage: 64 rows x 4 groups of 8
    int brow = tid >> 3, bcg = (tid & 7) * 8;   // B stage: 32 rows x 8 groups of 8
    const size_t abase = (size_t)(gm0 + arow) * K + acg;

    for (int k0 = 0; k0 < K; k0 += 32) {
        uint4 av = *(const uint4*)(A + abase + k0);
        uint4 bv = *(const uint4*)(Bw + (size_t)(k0 + brow) * N + gn0 + bcg);
        __syncthreads();                       // previous iter's LDS reads done
        *(uint4*)&As[arow][acg] = av;
        const bf16_t* bp = (const bf16_t*)&bv;
        #pragma unroll
        for (int j = 0; j < 8; ++j) Bs[bcg + j][brow] = bp[j];
        __syncthreads();

        int kc = (lane >> 4) * 8;
        bf16x8 a0 = *(const bf16x8*)&As[wr      + (lane & 15)][kc];
        bf16x8 a1 = *(const bf16x8*)&As[wr + 16 + (lane & 15)][kc];
        bf16x8 b0 = *(const bf16x8*)&Bs[wc      + (lane & 15)][kc];
        bf16x8 b1 = *(const bf16x8*)&Bs[wc + 16 + (lane & 15)][kc];
        acc[0][0] = __builtin_amdgcn_mfma_f32_16x16x32_bf16(a0, b0, acc[0][0], 0, 0, 0);
        acc[0][1] = __builtin_amdgcn_mfma_f32_16x16x32_bf16(a0, b1, acc[0][1], 0, 0, 0);
        acc[1][0] = __builtin_amdgcn_mfma_f32_16x16x32_bf16(a1, b0, acc[1][0], 0, 0, 0);
        acc[1][1] = __builtin_amdgcn_mfma_f32_16x16x32_bf16(a1, b1, acc[1][1], 0, 0, 0);
    }

    int crow = gm0 + wr + (lane >> 4) * 4;
    int ccol = gn0 + wc + (lane & 15);
    #pragma unroll
    for (int fi = 0; fi < 2; ++fi)
    #pragma unroll
    for (int fj = 0; fj < 2; ++fj)
    #pragma unroll
    for (int v = 0; v < 4; ++v) {
        int r = crow + fi * 16 + v;
        int c = ccol + fj * 16;
        float val = acc[fi][fj][v] + bias[c];
        if (EPI == 1) val = gelu_f(val);
        if (EPI == 2) {
            ((float*)Cout)[(size_t)r * N + c] = val + resid[(size_t)r * N + c];
        } else {
            ((bf16_t*)Cout)[(size_t)r * N + c] = (bf16_t)val;
        }
    }
}

// ---------------- Attention: one block per (b,h), full-row softmax ----------------
// qkv layout: [M, 2304] bf16, cols 0..767 = Q, 768.. = K, 1536.. = V (head h at h*64)
__global__ __launch_bounds__(256) void k_attn(const bf16_t* __restrict__ qkv,
                                              bf16_t* __restrict__ out) {
    __shared__ bf16_t VT[64][232];      // V^T: VT[d][lk], zero-padded lk>=197
    __shared__ bf16_t P[4][16][232];    // per-wave P tile, cols 208..223 zeroed once
    int tid = threadIdx.x, lane = tid & 63, wid = tid >> 6;
    int b = blockIdx.x / H_, hh = blockIdx.x % H_;
    const size_t base = (size_t)b * L_ * 2304 + hh * 64;

    // stage V^T
    for (int r = tid >> 3; r < L_; r += 32) {
        int cg = (tid & 7) * 8;
        bf16x8 vv = *(const bf16x8*)(qkv + base + (size_t)r * 2304 + 1536 + cg);
        #pragma unroll
        for (int j = 0; j < 8; ++j) VT[cg + j][r] = vv[j];
    }
    for (int i = tid; i < 64 * 35; i += 256) VT[i / 35][197 + i % 35] = (bf16_t)0.f;
    { // zero P pad cols 208..223 for own wave
        int r = lane & 15, c0 = 208 + (lane >> 4) * 4;
        #pragma unroll
        for (int j = 0; j < 4; ++j) P[wid][r][c0 + j] = (bf16_t)0.f;
    }
    __syncthreads();

    for (int s = wid; s < 13; s += 4) {      // 13 strips of 16 q-rows
        int q0 = s * 16;
        // Q A-frags (held for whole strip)
        int qr = q0 + (lane & 15); if (qr > L_ - 1) qr = L_ - 1;
        bf16x8 qf[2];
        #pragma unroll
        for (int kk = 0; kk < 2; ++kk)
            qf[kk] = *(const bf16x8*)(qkv + base + (size_t)qr * 2304 + kk * 32 + (lane >> 4) * 8);

        // S = Q K^T  (13 col-frags of 16)
        f32x4 sacc[13];
        #pragma unroll
        for (int nb = 0; nb < 13; ++nb) { f32x4 z = {0.f,0.f,0.f,0.f}; sacc[nb] = z; }
        #pragma unroll
        for (int nb = 0; nb < 13; ++nb) {
            int lk = nb * 16 + (lane & 15); if (lk > L_ - 1) lk = L_ - 1;
            #pragma unroll
            for (int kk = 0; kk < 2; ++kk) {
                bf16x8 kf = *(const bf16x8*)(qkv + base + (size_t)lk * 2304 + D_ + kk * 32 + (lane >> 4) * 8);
                sacc[nb] = __builtin_amdgcn_mfma_f32_16x16x32_bf16(qf[kk], kf, sacc[nb], 0, 0, 0);
            }
        }

        // softmax over row (cols spread across 16-lane group x 13 frags)
        float mx[4] = {-1e30f, -1e30f, -1e30f, -1e30f};
        float pv[13][4];
        #pragma unroll
        for (int nb = 0; nb < 13; ++nb) {
            bool valid = (nb * 16 + (lane & 15)) < L_;
            #pragma unroll
            for (int v = 0; v < 4; ++v) {
                float sv = valid ? sacc[nb][v] * 0.125f : -1e30f;
                pv[nb][v] = sv;
                mx[v] = fmaxf(mx[v], sv);
            }
        }
        #pragma unroll
        for (int o = 1; o < 16; o <<= 1) {
            #pragma unroll
            for (int v = 0; v < 4; ++v) mx[v] = fmaxf(mx[v], __shfl_xor(mx[v], o));
        }
        float sum[4] = {0.f, 0.f, 0.f, 0.f};
        #pragma unroll
        for (int nb = 0; nb < 13; ++nb) {
            bool valid = (nb * 16 + (lane & 15)) < L_;
            #pragma unroll
            for (int v = 0; v < 4; ++v) {
                float e = valid ? __expf(pv[nb][v] - mx[v]) : 0.f;
                pv[nb][v] = e; sum[v] += e;
            }
        }
        #pragma unroll
        for (int o = 1; o < 16; o <<= 1) {
            #pragma unroll
            for (int v = 0; v < 4; ++v) sum[v] += __shfl_xor(sum[v], o);
        }

        // P -> LDS (C layout -> A layout round trip)
        #pragma unroll
        for (int nb = 0; nb < 13; ++nb)
            #pragma unroll
            for (int v = 0; v < 4; ++v)
                P[wid][(lane >> 4) * 4 + v][nb * 16 + (lane & 15)] = (bf16_t)pv[nb][v];
        asm volatile("s_waitcnt lgkmcnt(0)" ::: "memory");

        // O = P V   (7 k-frags of 32, 4 n-frags of 16)
        f32x4 oacc[4];
        #pragma unroll
        for (int nb = 0; nb < 4; ++nb) { f32x4 z = {0.f,0.f,0.f,0.f}; oacc[nb] = z; }
        #pragma unroll
        for (int kk = 0; kk < 7; ++kk) {
            bf16x8 pf = *(const bf16x8*)&P[wid][lane & 15][kk * 32 + (lane >> 4) * 8];
            #pragma unroll
            for (int nb = 0; nb < 4; ++nb) {
                bf16x8 vf = *(const bf16x8*)&VT[nb * 16 + (lane & 15)][kk * 32 + (lane >> 4) * 8];
                oacc[nb] = __builtin_amdgcn_mfma_f32_16x16x32_bf16(pf, vf, oacc[nb], 0, 0, 0);
            }
        }

        float rs[4];
        #pragma unroll
        for (int v = 0; v < 4; ++v) rs[v] = 1.f / sum[v];
        #pragma unroll
        for (int nb = 0; nb < 4; ++nb)
            #pragma unroll
            for (int v = 0; v < 4; ++v) {
                int r = q0 + (lane >> 4) * 4 + v;
                if (r < L_)
                    out[((size_t)b * L_ + r) * D_ + hh * 64 + nb * 16 + (lane & 15)] =
                        (bf16_t)(oacc[nb][v] * rs[v]);
            }
    }
}

// ---------------- host orchestration ----------------
extern "C" void kernel_launch(void* const* d_in, const int* in_sizes, int n_in,
                              void* d_out, int out_size, void* d_ws, size_t ws_size,
                              hipStream_t stream) {
    const float* x     = (const float*)d_in[0];
    const float* pos   = (const float*)d_in[1];
    const float* ln1_g = (const float*)d_in[2];
    const float* ln1_b = (const float*)d_in[3];
    const float* Wq    = (const float*)d_in[4];
    const float* bq    = (const float*)d_in[5];
    const float* Wk    = (const float*)d_in[6];
    const float* bk    = (const float*)d_in[7];
    const float* Wv    = (const float*)d_in[8];
    const float* bv    = (const float*)d_in[9];
    const float* Wo    = (const float*)d_in[10];
    const float* bo    = (const float*)d_in[11];
    const float* ln2_g = (const float*)d_in[12];
    const float* ln2_b = (const float*)d_in[13];
    const float* W1    = (const float*)d_in[14];
    const float* b1    = (const float*)d_in[15];
    const float* W2    = (const float*)d_in[16];
    const float* b2    = (const float*)d_in[17];
    const float* lnf_g = (const float*)d_in[18];
    const float* lnf_b = (const float*)d_in[19];

    char* wsp = (char*)d_ws;
    size_t off = 0;
    auto alloc = [&](size_t bytes) -> void* {
        void* r = wsp + off;
        off += (bytes + 255) & ~(size_t)255;
        return r;
    };
    float*  h    = (float*) alloc((size_t)M_ * D_ * 4);
    bf16_t* y    = (bf16_t*)alloc((size_t)M_ * D_ * 2);
    bf16_t* qkv  = (bf16_t*)alloc((size_t)M_ * 2304 * 2);
    bf16_t* attn = (bf16_t*)alloc((size_t)M_ * D_ * 2);
    bf16_t* u    = (bf16_t*)alloc((size_t)M_ * F_ * 2);
    bf16_t* wqkv = (bf16_t*)alloc((size_t)D_ * 2304 * 2);
    bf16_t* wo   = (bf16_t*)alloc((size_t)D_ * D_ * 2);
    bf16_t* w1   = (bf16_t*)alloc((size_t)D_ * F_ * 2);
    bf16_t* w2   = (bf16_t*)alloc((size_t)F_ * D_ * 2);
    float*  bqkv = (float*) alloc(2304 * 4);
    (void)ws_size; (void)in_sizes; (void)n_in; (void)out_size;

    // h = x + pos
    {
        int n4 = M_ * D_ / 4;
        k_addpos4<<<(n4 + 255) / 256, 256, 0, stream>>>((const float4*)x, (const float4*)pos,
                                                        (float4*)h, n4, L_ * D_ / 4);
    }

    dim3 gQKV(M_ / 64, 2304 / 64);
    dim3 gO  (M_ / 64, D_ / 64);
    dim3 gF1 (M_ / 64, F_ / 64);
    dim3 gF2 (M_ / 64, D_ / 64);
    int convDD = (D_ * D_ / 4 + 255) / 256;
    int convDF = (D_ * F_ / 4 + 255) / 256;

    for (int l = 0; l < NL_; ++l) {
        k_pack_qkvw<<<convDD, 256, 0, stream>>>(Wq + (size_t)l * D_ * D_,
                                                Wk + (size_t)l * D_ * D_,
                                                Wv + (size_t)l * D_ * D_, wqkv);
        k_pack_qkvb<<<3, 256, 0, stream>>>(bq + l * D_, bk + l * D_, bv + l * D_, bqkv);
        k_conv4<<<convDD, 256, 0, stream>>>(Wo + (size_t)l * D_ * D_, wo, D_ * D_ / 4);
        k_conv4<<<convDF, 256, 0, stream>>>(W1 + (size_t)l * D_ * F_, w1, D_ * F_ / 4);
        k_conv4<<<convDF, 256, 0, stream>>>(W2 + (size_t)l * F_ * D_, w2, F_ * D_ / 4);

        k_ln<true><<<M_ / 4, 256, 0, stream>>>(h, ln1_g + l * D_, ln1_b + l * D_, y);
        k_gemm<0><<<gQKV, 256, 0, stream>>>(y, wqkv, bqkv, nullptr, qkv, D_, 2304);
        k_attn<<<B_ * H_, 256, 0, stream>>>(qkv, attn);
        k_gemm<2><<<gO, 256, 0, stream>>>(attn, wo, bo + l * D_, h, h, D_, D_);
        k_ln<true><<<M_ / 4, 256, 0, stream>>>(h, ln2_g + l * D_, ln2_b + l * D_, y);
        k_gemm<1><<<gF1, 256, 0, stream>>>(y, w1, b1 + (size_t)l * F_, nullptr, u, D_, F_);
        k_gemm<2><<<gF2, 256, 0, stream>>>(u, w2, b2 + l * D_, h, h, F_, D_);
    }
    k_ln<false><<<M_ / 4, 256, 0, stream>>>(h, lnf_g, lnf_b, d_out);
}

// Round 2
// 6849.272 us; speedup vs baseline: 1.5375x; 1.5375x over previous
//
#include <hip/hip_runtime.h>
#include <hip/hip_bf16.h>
#include <cmath>

// Problem dims (fixed)
#define B_ 64
#define L_ 197
#define D_ 768
#define H_ 12
#define NL_ 12
#define F_ 3072
#define M_ (B_*L_)          // 12608
#define MPAD_ 12672         // 128*99

typedef __bf16 bf16_t;
typedef __bf16 bf16x8 __attribute__((ext_vector_type(8)));
typedef __bf16 bf16x4 __attribute__((ext_vector_type(4)));
typedef float  f32x4  __attribute__((ext_vector_type(4)));

#define GPTR(p) ((const __attribute__((address_space(1))) void*)(p))
#define LPTR(p) ((__attribute__((address_space(3))) void*)(p))

__device__ __forceinline__ float gelu_f(float x) {
    return 0.5f * x * (1.f + erff(x * 0.70710678118654752440f));
}

// ---------------- elementwise: h = x + pos (fp32, float4) ----------------
__global__ __launch_bounds__(256) void k_addpos4(const float4* __restrict__ x,
                                                 const float4* __restrict__ pos,
                                                 float4* __restrict__ h,
                                                 int n4, int ld4) {
    int i = blockIdx.x * 256 + threadIdx.x;
    if (i < n4) {
        float4 a = x[i];
        float4 p = pos[i % ld4];
        float4 r; r.x = a.x + p.x; r.y = a.y + p.y; r.z = a.z + p.z; r.w = a.w + p.w;
        h[i] = r;
    }
}

// ---------------- fused fp32->bf16 convert + transpose: BT[n][k] = W[k][n] ----------------
// Tile 64x64. Grid (K/64, N/64), block 256.
__global__ __launch_bounds__(256) void k_convT(const float* __restrict__ W,
                                               bf16_t* __restrict__ BT,
                                               int K, int N) {
    __shared__ bf16_t s[64][72];
    int tid = threadIdx.x;
    int k0 = blockIdx.x * 64, n0 = blockIdx.y * 64;
    int kr = tid >> 4, nc = (tid & 15) * 4;
    #pragma unroll
    for (int i = 0; i < 4; ++i) {
        float4 v = *(const float4*)(W + (size_t)(k0 + kr + i*16) * N + n0 + nc);
        s[kr + i*16][nc]     = (bf16_t)v.x;
        s[kr + i*16][nc + 1] = (bf16_t)v.y;
        s[kr + i*16][nc + 2] = (bf16_t)v.z;
        s[kr + i*16][nc + 3] = (bf16_t)v.w;
    }
    __syncthreads();
    int nr = tid >> 3, kc = (tid & 7) * 8;
    #pragma unroll
    for (int i = 0; i < 2; ++i) {
        bf16x8 o;
        #pragma unroll
        for (int j = 0; j < 8; ++j) o[j] = s[kc + j][nr + i*32];
        *(bf16x8*)(BT + (size_t)(n0 + nr + i*32) * K + k0 + kc) = o;
    }
}

__global__ __launch_bounds__(256) void k_pack_qkvb(const float* __restrict__ bq,
                                                   const float* __restrict__ bk,
                                                   const float* __restrict__ bv,
                                                   float* __restrict__ bqkv) {
    int i = blockIdx.x * 256 + threadIdx.x;
    if (i < D_) { bqkv[i] = bq[i]; bqkv[D_ + i] = bk[i]; bqkv[2*D_ + i] = bv[i]; }
}

// ---------------- LayerNorm: one wave per row ----------------
template<bool BF16OUT>
__global__ __launch_bounds__(256) void k_ln(const float* __restrict__ x,
                                            const float* __restrict__ g,
                                            const float* __restrict__ bsh,
                                            void* __restrict__ out) {
    int wid = threadIdx.x >> 6, lane = threadIdx.x & 63;
    size_t row = (size_t)blockIdx.x * 4 + wid;
    const float4* xr = (const float4*)(x + row * D_);
    float4 v[3];
    float s = 0.f, sq = 0.f;
    #pragma unroll
    for (int i = 0; i < 3; ++i) {
        v[i] = xr[i*64 + lane];
        s  += v[i].x + v[i].y + v[i].z + v[i].w;
        sq += v[i].x*v[i].x + v[i].y*v[i].y + v[i].z*v[i].z + v[i].w*v[i].w;
    }
    #pragma unroll
    for (int o = 1; o < 64; o <<= 1) { s += __shfl_xor(s, o); sq += __shfl_xor(sq, o); }
    float mean = s * (1.f/768.f);
    float var  = sq * (1.f/768.f) - mean*mean;
    float rstd = rsqrtf(var + 1e-6f);
    const float4* g4 = (const float4*)g;
    const float4* b4 = (const float4*)bsh;
    #pragma unroll
    for (int i = 0; i < 3; ++i) {
        float4 gg = g4[i*64 + lane], bb = b4[i*64 + lane];
        float4 r;
        r.x = (v[i].x - mean)*rstd*gg.x + bb.x;
        r.y = (v[i].y - mean)*rstd*gg.y + bb.y;
        r.z = (v[i].z - mean)*rstd*gg.z + bb.z;
        r.w = (v[i].w - mean)*rstd*gg.w + bb.w;
        if (BF16OUT) {
            bf16x4 o4; o4[0]=(bf16_t)r.x; o4[1]=(bf16_t)r.y; o4[2]=(bf16_t)r.z; o4[3]=(bf16_t)r.w;
            ((bf16x4*)((bf16_t*)out + row * D_))[i*64 + lane] = o4;
        } else {
            ((float4*)out)[row * (D_/4) + i*64 + lane] = r;
        }
    }
}

// ---------------- GEMM (m97 structure): C = A[M,K] * BT[N,K]^T + bias ----------------
// 128x128 tile, BK=64, 4 waves (2x2), each wave 64x64 (4x4 frags), global_load_lds w=16.
// EPI: 0 = bias -> bf16 ; 1 = bias+gelu -> bf16 ; 2 = bias+resid(f32) -> f32
template<int EPI>
__global__ __launch_bounds__(256) void k_gemm_bt(const bf16_t* __restrict__ A,
                                                 const bf16_t* __restrict__ BT,
                                                 const float* __restrict__ bias,
                                                 const float* __restrict__ resid,
                                                 void* __restrict__ Cout,
                                                 int K, int N) {
    __shared__ bf16_t As[128 * 64];
    __shared__ bf16_t Bs[128 * 64];
    int tid = threadIdx.x, lane = tid & 63, wid = tid >> 6;
    int gm0 = blockIdx.x * 128, gn0 = blockIdx.y * 128;
    int wm = (wid >> 1) * 64, wn = (wid & 1) * 64;

    f32x4 acc[4][4];
    #pragma unroll
    for (int i = 0; i < 4; ++i)
        #pragma unroll
        for (int j = 0; j < 4; ++j) { f32x4 z = {0.f,0.f,0.f,0.f}; acc[i][j] = z; }

    // staging: wave w stages rows [w*32, w*32+32) of each tile; 4 insts x 1024B each.
    // inst i: lane l -> row w*32 + i*8 + l/8, col (l%8)*8  (LDS linear: elem off = lane*8)
    int srow = wid * 32 + (lane >> 3);
    int scol = (lane & 7) * 8;
    const bf16_t* agp = A  + (size_t)(gm0 + srow) * K + scol;
    const bf16_t* bgp = BT + (size_t)(gn0 + srow) * K + scol;

    for (int k0 = 0; k0 < K; k0 += 64) {
        __syncthreads();            // all waves done reading LDS from prev iter
        #pragma unroll
        for (int i = 0; i < 4; ++i) {
            __builtin_amdgcn_global_load_lds(GPTR(agp + k0 + (size_t)i*8*K),
                                             LPTR(As + wid*2048 + i*512), 16, 0, 0);
            __builtin_amdgcn_global_load_lds(GPTR(bgp + k0 + (size_t)i*8*K),
                                             LPTR(Bs + wid*2048 + i*512), 16, 0, 0);
        }
        __syncthreads();            // vmcnt(0) drained before barrier -> tile ready

        #pragma unroll
        for (int kc = 0; kc < 2; ++kc) {
            bf16x8 af[4], bfr[4];
            #pragma unroll
            for (int mi = 0; mi < 4; ++mi)
                af[mi] = *(const bf16x8*)&As[(wm + mi*16 + (lane & 15)) * 64 + kc*32 + (lane >> 4)*8];
            #pragma unroll
            for (int ni = 0; ni < 4; ++ni)
                bfr[ni] = *(const bf16x8*)&Bs[(wn + ni*16 + (lane & 15)) * 64 + kc*32 + (lane >> 4)*8];
            #pragma unroll
            for (int mi = 0; mi < 4; ++mi)
                #pragma unroll
                for (int ni = 0; ni < 4; ++ni)
                    acc[mi][ni] = __builtin_amdgcn_mfma_f32_16x16x32_bf16(af[mi], bfr[ni], acc[mi][ni], 0, 0, 0);
        }
    }

    int crow = gm0 + wm + (lane >> 4) * 4;
    int ccol = gn0 + wn + (lane & 15);
    #pragma unroll
    for (int mi = 0; mi < 4; ++mi)
        #pragma unroll
        for (int ni = 0; ni < 4; ++ni) {
            int c = ccol + ni * 16;
            float bval = bias[c];
            #pragma unroll
            for (int v = 0; v < 4; ++v) {
                int r = crow + mi * 16 + v;
                if (r < M_) {
                    float val = acc[mi][ni][v] + bval;
                    if (EPI == 1) val = gelu_f(val);
                    if (EPI == 2) {
                        ((float*)Cout)[(size_t)r * N + c] = val + resid[(size_t)r * N + c];
                    } else {
                        ((bf16_t*)Cout)[(size_t)r * N + c] = (bf16_t)val;
                    }
                }
            }
        }
}

// ---------------- Attention: one block per (b,h), full-row softmax ----------------
__global__ __launch_bounds__(256) void k_attn(const bf16_t* __restrict__ qkv,
                                              bf16_t* __restrict__ out) {
    __shared__ bf16_t VT[64][232];      // V^T, zero-padded lk>=197
    __shared__ bf16_t P[4][16][232];
    int tid = threadIdx.x, lane = tid & 63, wid = tid >> 6;
    int b = blockIdx.x / H_, hh = blockIdx.x % H_;
    const size_t base = (size_t)b * L_ * 2304 + hh * 64;

    for (int r = tid >> 3; r < L_; r += 32) {
        int cg = (tid & 7) * 8;
        bf16x8 vv = *(const bf16x8*)(qkv + base + (size_t)r * 2304 + 1536 + cg);
        #pragma unroll
        for (int j = 0; j < 8; ++j) VT[cg + j][r] = vv[j];
    }
    for (int i = tid; i < 64 * 35; i += 256) VT[i / 35][197 + i % 35] = (bf16_t)0.f;
    {
        int r = lane & 15, c0 = 208 + (lane >> 4) * 4;
        #pragma unroll
        for (int j = 0; j < 4; ++j) P[wid][r][c0 + j] = (bf16_t)0.f;
    }
    __syncthreads();

    for (int s = wid; s < 13; s += 4) {
        int q0 = s * 16;
        int qr = q0 + (lane & 15); if (qr > L_ - 1) qr = L_ - 1;
        bf16x8 qf[2];
        #pragma unroll
        for (int kk = 0; kk < 2; ++kk)
            qf[kk] = *(const bf16x8*)(qkv + base + (size_t)qr * 2304 + kk * 32 + (lane >> 4) * 8);

        f32x4 sacc[13];
        #pragma unroll
        for (int nb = 0; nb < 13; ++nb) { f32x4 z = {0.f,0.f,0.f,0.f}; sacc[nb] = z; }
        #pragma unroll
        for (int nb = 0; nb < 13; ++nb) {
            int lk = nb * 16 + (lane & 15); if (lk > L_ - 1) lk = L_ - 1;
            #pragma unroll
            for (int kk = 0; kk < 2; ++kk) {
                bf16x8 kf = *(const bf16x8*)(qkv + base + (size_t)lk * 2304 + D_ + kk * 32 + (lane >> 4) * 8);
                sacc[nb] = __builtin_amdgcn_mfma_f32_16x16x32_bf16(qf[kk], kf, sacc[nb], 0, 0, 0);
            }
        }

        float mx[4] = {-1e30f, -1e30f, -1e30f, -1e30f};
        float pv[13][4];
        #pragma unroll
        for (int nb = 0; nb < 13; ++nb) {
            bool valid = (nb * 16 + (lane & 15)) < L_;
            #pragma unroll
            for (int v = 0; v < 4; ++v) {
                float sv = valid ? sacc[nb][v] * 0.125f : -1e30f;
                pv[nb][v] = sv;
                mx[v] = fmaxf(mx[v], sv);
            }
        }
        #pragma unroll
        for (int o = 1; o < 16; o <<= 1) {
            #pragma unroll
            for (int v = 0; v < 4; ++v) mx[v] = fmaxf(mx[v], __shfl_xor(mx[v], o));
        }
        float sum[4] = {0.f, 0.f, 0.f, 0.f};
        #pragma unroll
        for (int nb = 0; nb < 13; ++nb) {
            bool valid = (nb * 16 + (lane & 15)) < L_;
            #pragma unroll
            for (int v = 0; v < 4; ++v) {
                float e = valid ? __expf(pv[nb][v] - mx[v]) : 0.f;
                pv[nb][v] = e; sum[v] += e;
            }
        }
        #pragma unroll
        for (int o = 1; o < 16; o <<= 1) {
            #pragma unroll
            for (int v = 0; v < 4; ++v) sum[v] += __shfl_xor(sum[v], o);
        }

        #pragma unroll
        for (int nb = 0; nb < 13; ++nb)
            #pragma unroll
            for (int v = 0; v < 4; ++v)
                P[wid][(lane >> 4) * 4 + v][nb * 16 + (lane & 15)] = (bf16_t)pv[nb][v];
        asm volatile("s_waitcnt lgkmcnt(0)" ::: "memory");

        f32x4 oacc[4];
        #pragma unroll
        for (int nb = 0; nb < 4; ++nb) { f32x4 z = {0.f,0.f,0.f,0.f}; oacc[nb] = z; }
        #pragma unroll
        for (int kk = 0; kk < 7; ++kk) {
            bf16x8 pf = *(const bf16x8*)&P[wid][lane & 15][kk * 32 + (lane >> 4) * 8];
            #pragma unroll
            for (int nb = 0; nb < 4; ++nb) {
                bf16x8 vf = *(const bf16x8*)&VT[nb * 16 + (lane & 15)][kk * 32 + (lane >> 4) * 8];
                oacc[nb] = __builtin_amdgcn_mfma_f32_16x16x32_bf16(pf, vf, oacc[nb], 0, 0, 0);
            }
        }

        float rs[4];
        #pragma unroll
        for (int v = 0; v < 4; ++v) rs[v] = 1.f / sum[v];
        #pragma unroll
        for (int nb = 0; nb < 4; ++nb)
            #pragma unroll
            for (int v = 0; v < 4; ++v) {
                int r = q0 + (lane >> 4) * 4 + v;
                if (r < L_)
                    out[((size_t)b * L_ + r) * D_ + hh * 64 + nb * 16 + (lane & 15)] =
                        (bf16_t)(oacc[nb][v] * rs[v]);
            }
    }
}

// ---------------- host orchestration ----------------
extern "C" void kernel_launch(void* const* d_in, const int* in_sizes, int n_in,
                              void* d_out, int out_size, void* d_ws, size_t ws_size,
                              hipStream_t stream) {
    const float* x     = (const float*)d_in[0];
    const float* pos   = (const float*)d_in[1];
    const float* ln1_g = (const float*)d_in[2];
    const float* ln1_b = (const float*)d_in[3];
    const float* Wq    = (const float*)d_in[4];
    const float* bq    = (const float*)d_in[5];
    const float* Wk    = (const float*)d_in[6];
    const float* bk    = (const float*)d_in[7];
    const float* Wv    = (const float*)d_in[8];
    const float* bv    = (const float*)d_in[9];
    const float* Wo    = (const float*)d_in[10];
    const float* bo    = (const float*)d_in[11];
    const float* ln2_g = (const float*)d_in[12];
    const float* ln2_b = (const float*)d_in[13];
    const float* W1    = (const float*)d_in[14];
    const float* b1    = (const float*)d_in[15];
    const float* W2    = (const float*)d_in[16];
    const float* b2    = (const float*)d_in[17];
    const float* lnf_g = (const float*)d_in[18];
    const float* lnf_b = (const float*)d_in[19];

    char* wsp = (char*)d_ws;
    size_t off = 0;
    auto alloc = [&](size_t bytes) -> void* {
        void* r = wsp + off;
        off += (bytes + 255) & ~(size_t)255;
        return r;
    };
    float*  h     = (float*) alloc((size_t)MPAD_ * D_ * 4);
    bf16_t* y     = (bf16_t*)alloc((size_t)MPAD_ * D_ * 2);
    bf16_t* qkv   = (bf16_t*)alloc((size_t)MPAD_ * 2304 * 2);
    bf16_t* attn  = (bf16_t*)alloc((size_t)MPAD_ * D_ * 2);
    bf16_t* u     = (bf16_t*)alloc((size_t)MPAD_ * F_ * 2);
    bf16_t* wqkvT = (bf16_t*)alloc((size_t)2304 * D_ * 2);  // [2304][768]
    bf16_t* woT   = (bf16_t*)alloc((size_t)D_ * D_ * 2);    // [768][768]
    bf16_t* w1T   = (bf16_t*)alloc((size_t)F_ * D_ * 2);    // [3072][768]
    bf16_t* w2T   = (bf16_t*)alloc((size_t)D_ * F_ * 2);    // [768][3072]
    float*  bqkv  = (float*) alloc(2304 * 4);
    (void)ws_size; (void)in_sizes; (void)n_in; (void)out_size;

    {
        int n4 = M_ * D_ / 4;
        k_addpos4<<<(n4 + 255) / 256, 256, 0, stream>>>((const float4*)x, (const float4*)pos,
                                                        (float4*)h, n4, L_ * D_ / 4);
    }

    dim3 gQKV(MPAD_ / 128, 2304 / 128);
    dim3 gO  (MPAD_ / 128, D_ / 128);
    dim3 gF1 (MPAD_ / 128, F_ / 128);
    dim3 gF2 (MPAD_ / 128, D_ / 128);
    dim3 tDD (D_ / 64, D_ / 64);
    dim3 tDF (D_ / 64, F_ / 64);
    dim3 tFD (F_ / 64, D_ / 64);

    for (int l = 0; l < NL_; ++l) {
        k_convT<<<tDD, 256, 0, stream>>>(Wq + (size_t)l * D_ * D_, wqkvT,                     D_, D_);
        k_convT<<<tDD, 256, 0, stream>>>(Wk + (size_t)l * D_ * D_, wqkvT + (size_t)768 * D_,  D_, D_);
        k_convT<<<tDD, 256, 0, stream>>>(Wv + (size_t)l * D_ * D_, wqkvT + (size_t)1536 * D_, D_, D_);
        k_convT<<<tDD, 256, 0, stream>>>(Wo + (size_t)l * D_ * D_, woT, D_, D_);
        k_convT<<<tDF, 256, 0, stream>>>(W1 + (size_t)l * D_ * F_, w1T, D_, F_);
        k_convT<<<tFD, 256, 0, stream>>>(W2 + (size_t)l * F_ * D_, w2T, F_, D_);
        k_pack_qkvb<<<3, 256, 0, stream>>>(bq + l * D_, bk + l * D_, bv + l * D_, bqkv);

        k_ln<true><<<M_ / 4, 256, 0, stream>>>(h, ln1_g + l * D_, ln1_b + l * D_, y);
        k_gemm_bt<0><<<gQKV, 256, 0, stream>>>(y, wqkvT, bqkv, nullptr, qkv, D_, 2304);
        k_attn<<<B_ * H_, 256, 0, stream>>>(qkv, attn);
        k_gemm_bt<2><<<gO, 256, 0, stream>>>(attn, woT, bo + l * D_, h, h, D_, D_);
        k_ln<true><<<M_ / 4, 256, 0, stream>>>(h, ln2_g + l * D_, ln2_b + l * D_, y);
        k_gemm_bt<1><<<gF1, 256, 0, stream>>>(y, w1T, b1 + (size_t)l * F_, nullptr, u, D_, F_);
        k_gemm_bt<2><<<gF2, 256, 0, stream>>>(u, w2T, b2 + l * D_, h, h, F_, D_);
    }
    k_ln<false><<<M_ / 4, 256, 0, stream>>>(h, lnf_g, lnf_b, d_out);
}

// Round 3
// 6487.168 us; speedup vs baseline: 1.6233x; 1.0558x over previous
//
#include <hip/hip_runtime.h>
#include <hip/hip_bf16.h>
#include <cmath>

// Problem dims (fixed)
#define B_ 64
#define L_ 197
#define D_ 768
#define H_ 12
#define NL_ 12
#define F_ 3072
#define M_ (B_*L_)          // 12608
#define MPAD_ 12800         // 256*50

typedef __bf16 bf16_t;
typedef __bf16 bf16x8 __attribute__((ext_vector_type(8)));
typedef __bf16 bf16x4 __attribute__((ext_vector_type(4)));
typedef float  f32x4  __attribute__((ext_vector_type(4)));

#define GPTR(p) ((const __attribute__((address_space(1))) void*)(p))
#define LPTR(p) ((__attribute__((address_space(3))) void*)(p))

__device__ __forceinline__ float gelu_f(float x) {
    return 0.5f * x * (1.f + erff(x * 0.70710678118654752440f));
}

template<int N> __device__ __forceinline__ void waitvm() {
    if constexpr (N == 0)      asm volatile("s_waitcnt vmcnt(0)" ::: "memory");
    else if constexpr (N == 6) asm volatile("s_waitcnt vmcnt(6)" ::: "memory");
    else if constexpr (N == 8) asm volatile("s_waitcnt vmcnt(8)" ::: "memory");
    __builtin_amdgcn_sched_barrier(0);
}

// ---------------- elementwise: h = x + pos (fp32, float4) ----------------
__global__ __launch_bounds__(256) void k_addpos4(const float4* __restrict__ x,
                                                 const float4* __restrict__ pos,
                                                 float4* __restrict__ h,
                                                 int n4, int ld4) {
    int i = blockIdx.x * 256 + threadIdx.x;
    if (i < n4) {
        float4 a = x[i];
        float4 p = pos[i % ld4];
        float4 r; r.x = a.x + p.x; r.y = a.y + p.y; r.z = a.z + p.z; r.w = a.w + p.w;
        h[i] = r;
    }
}

// ---------------- fused fp32->bf16 convert + transpose: BT[n][k] = W[k][n] ----------------
__global__ __launch_bounds__(256) void k_convT(const float* __restrict__ W,
                                               bf16_t* __restrict__ BT,
                                               int K, int N) {
    __shared__ bf16_t s[64][72];
    int tid = threadIdx.x;
    int k0 = blockIdx.x * 64, n0 = blockIdx.y * 64;
    int kr = tid >> 4, nc = (tid & 15) * 4;
    #pragma unroll
    for (int i = 0; i < 4; ++i) {
        float4 v = *(const float4*)(W + (size_t)(k0 + kr + i*16) * N + n0 + nc);
        s[kr + i*16][nc]     = (bf16_t)v.x;
        s[kr + i*16][nc + 1] = (bf16_t)v.y;
        s[kr + i*16][nc + 2] = (bf16_t)v.z;
        s[kr + i*16][nc + 3] = (bf16_t)v.w;
    }
    __syncthreads();
    int nr = tid >> 3, kc = (tid & 7) * 8;
    #pragma unroll
    for (int i = 0; i < 2; ++i) {
        bf16x8 o;
        #pragma unroll
        for (int j = 0; j < 8; ++j) o[j] = s[kc + j][nr + i*32];
        *(bf16x8*)(BT + (size_t)(n0 + nr + i*32) * K + k0 + kc) = o;
    }
}

__global__ __launch_bounds__(256) void k_pack_qkvb(const float* __restrict__ bq,
                                                   const float* __restrict__ bk,
                                                   const float* __restrict__ bv,
                                                   float* __restrict__ bqkv) {
    int i = blockIdx.x * 256 + threadIdx.x;
    if (i < D_) { bqkv[i] = bq[i]; bqkv[D_ + i] = bk[i]; bqkv[2*D_ + i] = bv[i]; }
}

// ---------------- LayerNorm: one wave per row ----------------
template<bool BF16OUT>
__global__ __launch_bounds__(256) void k_ln(const float* __restrict__ x,
                                            const float* __restrict__ g,
                                            const float* __restrict__ bsh,
                                            void* __restrict__ out) {
    int wid = threadIdx.x >> 6, lane = threadIdx.x & 63;
    size_t row = (size_t)blockIdx.x * 4 + wid;
    const float4* xr = (const float4*)(x + row * D_);
    float4 v[3];
    float s = 0.f, sq = 0.f;
    #pragma unroll
    for (int i = 0; i < 3; ++i) {
        v[i] = xr[i*64 + lane];
        s  += v[i].x + v[i].y + v[i].z + v[i].w;
        sq += v[i].x*v[i].x + v[i].y*v[i].y + v[i].z*v[i].z + v[i].w*v[i].w;
    }
    #pragma unroll
    for (int o = 1; o < 64; o <<= 1) { s += __shfl_xor(s, o); sq += __shfl_xor(sq, o); }
    float mean = s * (1.f/768.f);
    float var  = sq * (1.f/768.f) - mean*mean;
    float rstd = rsqrtf(var + 1e-6f);
    const float4* g4 = (const float4*)g;
    const float4* b4 = (const float4*)bsh;
    #pragma unroll
    for (int i = 0; i < 3; ++i) {
        float4 gg = g4[i*64 + lane], bb = b4[i*64 + lane];
        float4 r;
        r.x = (v[i].x - mean)*rstd*gg.x + bb.x;
        r.y = (v[i].y - mean)*rstd*gg.y + bb.y;
        r.z = (v[i].z - mean)*rstd*gg.z + bb.z;
        r.w = (v[i].w - mean)*rstd*gg.w + bb.w;
        if (BF16OUT) {
            bf16x4 o4; o4[0]=(bf16_t)r.x; o4[1]=(bf16_t)r.y; o4[2]=(bf16_t)r.z; o4[3]=(bf16_t)r.w;
            ((bf16x4*)((bf16_t*)out + row * D_))[i*64 + lane] = o4;
        } else {
            ((float4*)out)[row * (D_/4) + i*64 + lane] = r;
        }
    }
}

// ---------------- GEMM 256-tile, 4-phase/K-tile, counted vmcnt, T2 swizzle ----------------
// C[M,N] = A[M,K] * BT[N,K]^T + bias.  BM=256, BK=64, BN in {256,128}.
// 512 threads = 8 waves (2M x 4N). Per-wave 128 x WN (WN=BN/4).
// EPI: 0 = bias->bf16 ; 1 = bias+gelu->bf16 ; 2 = bias+resid(f32)->f32
template<int EPI, int BN>
__global__ __launch_bounds__(512, 2) void k_gemm256(
        const bf16_t* __restrict__ A, const bf16_t* __restrict__ BT,
        const float* __restrict__ bias, const float* __restrict__ resid,
        void* __restrict__ Cout, int K, int N, int NB) {
    constexpr int WN = BN / 4;     // 64 or 32
    constexpr int NF = WN / 16;    // 4 or 2 N-frags per wave
    constexpr int NH = NF / 2;     // frags per N-half: 2 or 1
    constexpr int BL = BN / 64;    // B stage insts/wave: 4 or 2
    constexpr int L  = 4 + BL;     // loads per tile per wave (vmcnt unit)

    __shared__ bf16_t As[2][256 * 64];
    __shared__ bf16_t Bs[2][BN * 64];

    const int tid = threadIdx.x, lane = tid & 63, wid = tid >> 6;
    const int g = lane >> 4, e = lane & 7, fr = lane & 15;
    const int wm = (wid >> 2) * 128, wn = (wid & 3) * WN;

    // bijective XCD swizzle (m204), then bx = wg/NB (M-panel), by = wg%NB (N fastest)
    int nwg = (int)gridDim.x, orig = (int)blockIdx.x;
    int qq = nwg >> 3, rr = nwg & 7;
    int xcd = orig & 7, idx = orig >> 3;
    int wg = (xcd < rr ? xcd * (qq + 1) : rr * (qq + 1) + (xcd - rr) * qq) + idx;
    int bx = wg / NB, by = wg - bx * NB;
    const int gm0 = bx * 256, gn0 = by * BN;

    // staging geometry: within an 8-row inst block, lane l -> row l>>3, chunk l&7.
    // swizzle (T2): LDS chunk b of row r holds global chunk b^(r&7).
    const int srl = lane >> 3, sb = lane & 7;
    const int sc = (sb ^ srl) * 8;     // pre-swizzled source col (elems)

    f32x4 acc[8][NF];
    #pragma unroll
    for (int i = 0; i < 8; ++i)
        #pragma unroll
        for (int j = 0; j < NF; ++j) acc[i][j] = (f32x4){0.f, 0.f, 0.f, 0.f};

    const bf16_t* a_src = A  + (size_t)(gm0 + wid * 32 + srl) * K + sc;
    const bf16_t* b_src = BT + (size_t)(gn0 + wid * (BN / 8) + srl) * K + sc;

    auto stage = [&](int t, int p) {
        const int k0 = t * 64;
        #pragma unroll
        for (int i = 0; i < 4; ++i)
            __builtin_amdgcn_global_load_lds(GPTR(a_src + (size_t)(i * 8) * K + k0),
                                             LPTR(&As[p][(wid * 32 + i * 8) * 64]), 16, 0, 0);
        #pragma unroll
        for (int i = 0; i < BL; ++i)
            __builtin_amdgcn_global_load_lds(GPTR(b_src + (size_t)(i * 8) * K + k0),
                                             LPTR(&Bs[p][(wid * (BN / 8) + i * 8) * 64]), 16, 0, 0);
    };
    // swizzled ds_reads: row's chunk c is at LDS chunk c^(row&7); row&7 == e here.
    auto rdA = [&](int p, int mh, bf16x8* afr) {
        #pragma unroll
        for (int mi = 0; mi < 4; ++mi)
            #pragma unroll
            for (int kc = 0; kc < 2; ++kc)
                afr[mi*2+kc] = *(const bf16x8*)&As[p][(wm + mh*64 + mi*16 + fr) * 64 + (((kc*4 + g) ^ e) * 8)];
    };
    auto rdB = [&](int p, int nh, bf16x8* bfr) {
        #pragma unroll
        for (int ni = 0; ni < NH; ++ni)
            #pragma unroll
            for (int kc = 0; kc < 2; ++kc)
                bfr[ni*2+kc] = *(const bf16x8*)&Bs[p][(wn + nh*(WN/2) + ni*16 + fr) * 64 + (((kc*4 + g) ^ e) * 8)];
    };
    auto mmac = [&](int mh, int nh, bf16x8* afr, bf16x8* bfr) {
        #pragma unroll
        for (int mi = 0; mi < 4; ++mi)
            #pragma unroll
            for (int ni = 0; ni < NH; ++ni)
                #pragma unroll
                for (int kc = 0; kc < 2; ++kc)
                    acc[mh*4+mi][nh*NH+ni] = __builtin_amdgcn_mfma_f32_16x16x32_bf16(
                        afr[mi*2+kc], bfr[ni*2+kc], acc[mh*4+mi][nh*NH+ni], 0, 0, 0);
    };

    // prologue: tiles 0 and 1 in flight; wait tile 0 resident
    stage(0, 0);
    stage(1, 1);
    waitvm<L>();
    __builtin_amdgcn_s_barrier();

    const int NT = K >> 6;
    bf16x8 afr[8], b0r[2 * NH], b1r[2 * NH];
    for (int t = 0; t < NT; ++t) {
        const int p = t & 1;
        // P1: Q(0,0)
        rdA(p, 0, afr); rdB(p, 0, b0r);
        __builtin_amdgcn_s_setprio(1); mmac(0, 0, afr, b0r); __builtin_amdgcn_s_setprio(0);
        __builtin_amdgcn_s_barrier();
        // P2: Q(0,1)
        rdB(p, 1, b1r);
        __builtin_amdgcn_s_setprio(1); mmac(0, 1, afr, b1r); __builtin_amdgcn_s_setprio(0);
        __builtin_amdgcn_s_barrier();
        // P3: Q(1,0) — after this barrier, buf p is dead for all waves
        rdA(p, 1, afr);
        __builtin_amdgcn_s_setprio(1); mmac(1, 0, afr, b0r); __builtin_amdgcn_s_setprio(0);
        asm volatile("s_waitcnt lgkmcnt(0)" ::: "memory");
        __builtin_amdgcn_sched_barrier(0);
        __builtin_amdgcn_s_barrier();
        // P4: stage t+2 into buf p; Q(1,1); counted vmcnt ensures tile t+1 resident
        if (t + 2 < NT) stage(t + 2, p);
        __builtin_amdgcn_s_setprio(1); mmac(1, 1, afr, b1r); __builtin_amdgcn_s_setprio(0);
        if (t + 2 < NT) waitvm<L>(); else waitvm<0>();
        __builtin_amdgcn_s_barrier();
    }

    // epilogue
    const int crow = gm0 + wm + g * 4;
    const int ccol = gn0 + wn + fr;
    #pragma unroll
    for (int mi = 0; mi < 8; ++mi)
        #pragma unroll
        for (int ni = 0; ni < NF; ++ni) {
            const int c = ccol + ni * 16;
            const float bval = bias[c];
            #pragma unroll
            for (int v = 0; v < 4; ++v) {
                const int rw = crow + mi * 16 + v;
                if (rw < M_) {
                    float val = acc[mi][ni][v] + bval;
                    if (EPI == 1) val = gelu_f(val);
                    if (EPI == 2) {
                        ((float*)Cout)[(size_t)rw * N + c] = val + resid[(size_t)rw * N + c];
                    } else {
                        ((bf16_t*)Cout)[(size_t)rw * N + c] = (bf16_t)val;
                    }
                }
            }
        }
}

// ---------------- Attention: one block per (b,h), full-row softmax ----------------
__global__ __launch_bounds__(256) void k_attn(const bf16_t* __restrict__ qkv,
                                              bf16_t* __restrict__ out) {
    __shared__ bf16_t VT[64][232];
    __shared__ bf16_t P[4][16][232];
    int tid = threadIdx.x, lane = tid & 63, wid = tid >> 6;
    int b = blockIdx.x / H_, hh = blockIdx.x % H_;
    const size_t base = (size_t)b * L_ * 2304 + hh * 64;

    for (int r = tid >> 3; r < L_; r += 32) {
        int cg = (tid & 7) * 8;
        bf16x8 vv = *(const bf16x8*)(qkv + base + (size_t)r * 2304 + 1536 + cg);
        #pragma unroll
        for (int j = 0; j < 8; ++j) VT[cg + j][r] = vv[j];
    }
    for (int i = tid; i < 64 * 35; i += 256) VT[i / 35][197 + i % 35] = (bf16_t)0.f;
    {
        int r = lane & 15, c0 = 208 + (lane >> 4) * 4;
        #pragma unroll
        for (int j = 0; j < 4; ++j) P[wid][r][c0 + j] = (bf16_t)0.f;
    }
    __syncthreads();

    for (int s = wid; s < 13; s += 4) {
        int q0 = s * 16;
        int qr = q0 + (lane & 15); if (qr > L_ - 1) qr = L_ - 1;
        bf16x8 qf[2];
        #pragma unroll
        for (int kk = 0; kk < 2; ++kk)
            qf[kk] = *(const bf16x8*)(qkv + base + (size_t)qr * 2304 + kk * 32 + (lane >> 4) * 8);

        f32x4 sacc[13];
        #pragma unroll
        for (int nb = 0; nb < 13; ++nb) { f32x4 z = {0.f,0.f,0.f,0.f}; sacc[nb] = z; }
        #pragma unroll
        for (int nb = 0; nb < 13; ++nb) {
            int lk = nb * 16 + (lane & 15); if (lk > L_ - 1) lk = L_ - 1;
            #pragma unroll
            for (int kk = 0; kk < 2; ++kk) {
                bf16x8 kf = *(const bf16x8*)(qkv + base + (size_t)lk * 2304 + D_ + kk * 32 + (lane >> 4) * 8);
                sacc[nb] = __builtin_amdgcn_mfma_f32_16x16x32_bf16(qf[kk], kf, sacc[nb], 0, 0, 0);
            }
        }

        float mx[4] = {-1e30f, -1e30f, -1e30f, -1e30f};
        float pv[13][4];
        #pragma unroll
        for (int nb = 0; nb < 13; ++nb) {
            bool valid = (nb * 16 + (lane & 15)) < L_;
            #pragma unroll
            for (int v = 0; v < 4; ++v) {
                float sv = valid ? sacc[nb][v] * 0.125f : -1e30f;
                pv[nb][v] = sv;
                mx[v] = fmaxf(mx[v], sv);
            }
        }
        #pragma unroll
        for (int o = 1; o < 16; o <<= 1) {
            #pragma unroll
            for (int v = 0; v < 4; ++v) mx[v] = fmaxf(mx[v], __shfl_xor(mx[v], o));
        }
        float sum[4] = {0.f, 0.f, 0.f, 0.f};
        #pragma unroll
        for (int nb = 0; nb < 13; ++nb) {
            bool valid = (nb * 16 + (lane & 15)) < L_;
            #pragma unroll
            for (int v = 0; v < 4; ++v) {
                float e2 = valid ? __expf(pv[nb][v] - mx[v]) : 0.f;
                pv[nb][v] = e2; sum[v] += e2;
            }
        }
        #pragma unroll
        for (int o = 1; o < 16; o <<= 1) {
            #pragma unroll
            for (int v = 0; v < 4; ++v) sum[v] += __shfl_xor(sum[v], o);
        }

        #pragma unroll
        for (int nb = 0; nb < 13; ++nb)
            #pragma unroll
            for (int v = 0; v < 4; ++v)
                P[wid][(lane >> 4) * 4 + v][nb * 16 + (lane & 15)] = (bf16_t)pv[nb][v];
        asm volatile("s_waitcnt lgkmcnt(0)" ::: "memory");

        f32x4 oacc[4];
        #pragma unroll
        for (int nb = 0; nb < 4; ++nb) { f32x4 z = {0.f,0.f,0.f,0.f}; oacc[nb] = z; }
        #pragma unroll
        for (int kk = 0; kk < 7; ++kk) {
            bf16x8 pf = *(const bf16x8*)&P[wid][lane & 15][kk * 32 + (lane >> 4) * 8];
            #pragma unroll
            for (int nb = 0; nb < 4; ++nb) {
                bf16x8 vf = *(const bf16x8*)&VT[nb * 16 + (lane & 15)][kk * 32 + (lane >> 4) * 8];
                oacc[nb] = __builtin_amdgcn_mfma_f32_16x16x32_bf16(pf, vf, oacc[nb], 0, 0, 0);
            }
        }

        float rs[4];
        #pragma unroll
        for (int v = 0; v < 4; ++v) rs[v] = 1.f / sum[v];
        #pragma unroll
        for (int nb = 0; nb < 4; ++nb)
            #pragma unroll
            for (int v = 0; v < 4; ++v) {
                int r = q0 + (lane >> 4) * 4 + v;
                if (r < L_)
                    out[((size_t)b * L_ + r) * D_ + hh * 64 + nb * 16 + (lane & 15)] =
                        (bf16_t)(oacc[nb][v] * rs[v]);
            }
    }
}

// ---------------- host orchestration ----------------
extern "C" void kernel_launch(void* const* d_in, const int* in_sizes, int n_in,
                              void* d_out, int out_size, void* d_ws, size_t ws_size,
                              hipStream_t stream) {
    const float* x     = (const float*)d_in[0];
    const float* pos   = (const float*)d_in[1];
    const float* ln1_g = (const float*)d_in[2];
    const float* ln1_b = (const float*)d_in[3];
    const float* Wq    = (const float*)d_in[4];
    const float* bq    = (const float*)d_in[5];
    const float* Wk    = (const float*)d_in[6];
    const float* bk    = (const float*)d_in[7];
    const float* Wv    = (const float*)d_in[8];
    const float* bv    = (const float*)d_in[9];
    const float* Wo    = (const float*)d_in[10];
    const float* bo    = (const float*)d_in[11];
    const float* ln2_g = (const float*)d_in[12];
    const float* ln2_b = (const float*)d_in[13];
    const float* W1    = (const float*)d_in[14];
    const float* b1    = (const float*)d_in[15];
    const float* W2    = (const float*)d_in[16];
    const float* b2    = (const float*)d_in[17];
    const float* lnf_g = (const float*)d_in[18];
    const float* lnf_b = (const float*)d_in[19];

    char* wsp = (char*)d_ws;
    size_t off = 0;
    auto alloc = [&](size_t bytes) -> void* {
        void* r = wsp + off;
        off += (bytes + 255) & ~(size_t)255;
        return r;
    };
    float*  h     = (float*) alloc((size_t)M_ * D_ * 4);
    bf16_t* y     = (bf16_t*)alloc((size_t)MPAD_ * D_ * 2);
    bf16_t* qkv   = (bf16_t*)alloc((size_t)M_ * 2304 * 2);
    bf16_t* attn  = (bf16_t*)alloc((size_t)MPAD_ * D_ * 2);
    bf16_t* u     = (bf16_t*)alloc((size_t)MPAD_ * F_ * 2);
    bf16_t* wqkvT = (bf16_t*)alloc((size_t)2304 * D_ * 2);
    bf16_t* woT   = (bf16_t*)alloc((size_t)D_ * D_ * 2);
    bf16_t* w1T   = (bf16_t*)alloc((size_t)F_ * D_ * 2);
    bf16_t* w2T   = (bf16_t*)alloc((size_t)D_ * F_ * 2);
    float*  bqkv  = (float*) alloc(2304 * 4);
    (void)ws_size; (void)in_sizes; (void)n_in; (void)out_size;

    {
        int n4 = M_ * D_ / 4;
        k_addpos4<<<(n4 + 255) / 256, 256, 0, stream>>>((const float4*)x, (const float4*)pos,
                                                        (float4*)h, n4, L_ * D_ / 4);
    }

    dim3 tDD (D_ / 64, D_ / 64);
    dim3 tDF (D_ / 64, F_ / 64);
    dim3 tFD (F_ / 64, D_ / 64);

    for (int l = 0; l < NL_; ++l) {
        k_convT<<<tDD, 256, 0, stream>>>(Wq + (size_t)l * D_ * D_, wqkvT,                     D_, D_);
        k_convT<<<tDD, 256, 0, stream>>>(Wk + (size_t)l * D_ * D_, wqkvT + (size_t)768 * D_,  D_, D_);
        k_convT<<<tDD, 256, 0, stream>>>(Wv + (size_t)l * D_ * D_, wqkvT + (size_t)1536 * D_, D_, D_);
        k_convT<<<tDD, 256, 0, stream>>>(Wo + (size_t)l * D_ * D_, woT, D_, D_);
        k_convT<<<tDF, 256, 0, stream>>>(W1 + (size_t)l * D_ * F_, w1T, D_, F_);
        k_convT<<<tFD, 256, 0, stream>>>(W2 + (size_t)l * F_ * D_, w2T, F_, D_);
        k_pack_qkvb<<<3, 256, 0, stream>>>(bq + l * D_, bk + l * D_, bv + l * D_, bqkv);

        k_ln<true><<<M_ / 4, 256, 0, stream>>>(h, ln1_g + l * D_, ln1_b + l * D_, y);
        k_gemm256<0, 256><<<dim3(50 * 9),  512, 0, stream>>>(y,    wqkvT, bqkv,              nullptr, qkv, D_, 2304, 9);
        k_attn<<<B_ * H_, 256, 0, stream>>>(qkv, attn);
        k_gemm256<2, 128><<<dim3(50 * 6),  512, 0, stream>>>(attn, woT,   bo + l * D_,       h,       h,   D_, D_,   6);
        k_ln<true><<<M_ / 4, 256, 0, stream>>>(h, ln2_g + l * D_, ln2_b + l * D_, y);
        k_gemm256<1, 256><<<dim3(50 * 12), 512, 0, stream>>>(y,    w1T,   b1 + (size_t)l*F_, nullptr, u,   D_, F_,   12);
        k_gemm256<2, 128><<<dim3(50 * 6),  512, 0, stream>>>(u,    w2T,   b2 + l * D_,       h,       h,   F_, D_,   6);
    }
    k_ln<false><<<M_ / 4, 256, 0, stream>>>(h, lnf_g, lnf_b, d_out);
}

// Round 4
// 5698.666 us; speedup vs baseline: 1.8479x; 1.1384x over previous
//
#include <hip/hip_runtime.h>
#include <hip/hip_bf16.h>
#include <cmath>

// Problem dims (fixed)
#define B_ 64
#define L_ 197
#define D_ 768
#define H_ 12
#define NL_ 12
#define F_ 3072
#define M_ (B_*L_)          // 12608
#define MPAD_ 12672         // 128*99

typedef __bf16 bf16_t;
typedef __bf16 bf16x8 __attribute__((ext_vector_type(8)));
typedef __bf16 bf16x4 __attribute__((ext_vector_type(4)));
typedef float  f32x4  __attribute__((ext_vector_type(4)));

#define GPTR(p) ((const __attribute__((address_space(1))) void*)(p))
#define LPTR(p) ((__attribute__((address_space(3))) void*)(p))

__device__ __forceinline__ float gelu_f(float x) {
    return 0.5f * x * (1.f + erff(x * 0.70710678118654752440f));
}

template<int N> __device__ __forceinline__ void waitvm() {
    if constexpr (N == 0)      asm volatile("s_waitcnt vmcnt(0)" ::: "memory");
    else if constexpr (N == 8) asm volatile("s_waitcnt vmcnt(8)" ::: "memory");
    __builtin_amdgcn_sched_barrier(0);
}

// ---------------- elementwise: h = x + pos (fp32, float4) ----------------
__global__ __launch_bounds__(256) void k_addpos4(const float4* __restrict__ x,
                                                 const float4* __restrict__ pos,
                                                 float4* __restrict__ h,
                                                 int n4, int ld4) {
    int i = blockIdx.x * 256 + threadIdx.x;
    if (i < n4) {
        float4 a = x[i];
        float4 p = pos[i % ld4];
        float4 r; r.x = a.x + p.x; r.y = a.y + p.y; r.z = a.z + p.z; r.w = a.w + p.w;
        h[i] = r;
    }
}

// ---------------- fused fp32->bf16 convert + transpose: BT[n][k] = W[k][n] ----------------
__global__ __launch_bounds__(256) void k_convT(const float* __restrict__ W,
                                               bf16_t* __restrict__ BT,
                                               int K, int N) {
    __shared__ bf16_t s[64][72];
    int tid = threadIdx.x;
    int k0 = blockIdx.x * 64, n0 = blockIdx.y * 64;
    int kr = tid >> 4, nc = (tid & 15) * 4;
    #pragma unroll
    for (int i = 0; i < 4; ++i) {
        float4 v = *(const float4*)(W + (size_t)(k0 + kr + i*16) * N + n0 + nc);
        s[kr + i*16][nc]     = (bf16_t)v.x;
        s[kr + i*16][nc + 1] = (bf16_t)v.y;
        s[kr + i*16][nc + 2] = (bf16_t)v.z;
        s[kr + i*16][nc + 3] = (bf16_t)v.w;
    }
    __syncthreads();
    int nr = tid >> 3, kc = (tid & 7) * 8;
    #pragma unroll
    for (int i = 0; i < 2; ++i) {
        bf16x8 o;
        #pragma unroll
        for (int j = 0; j < 8; ++j) o[j] = s[kc + j][nr + i*32];
        *(bf16x8*)(BT + (size_t)(n0 + nr + i*32) * K + k0 + kc) = o;
    }
}

__global__ __launch_bounds__(256) void k_pack_qkvb(const float* __restrict__ bq,
                                                   const float* __restrict__ bk,
                                                   const float* __restrict__ bv,
                                                   float* __restrict__ bqkv) {
    int i = blockIdx.x * 256 + threadIdx.x;
    if (i < D_) { bqkv[i] = bq[i]; bqkv[D_ + i] = bk[i]; bqkv[2*D_ + i] = bv[i]; }
}

// ---------------- LayerNorm: one wave per row ----------------
template<bool BF16OUT>
__global__ __launch_bounds__(256) void k_ln(const float* __restrict__ x,
                                            const float* __restrict__ g,
                                            const float* __restrict__ bsh,
                                            void* __restrict__ out) {
    int wid = threadIdx.x >> 6, lane = threadIdx.x & 63;
    size_t row = (size_t)blockIdx.x * 4 + wid;
    const float4* xr = (const float4*)(x + row * D_);
    float4 v[3];
    float s = 0.f, sq = 0.f;
    #pragma unroll
    for (int i = 0; i < 3; ++i) {
        v[i] = xr[i*64 + lane];
        s  += v[i].x + v[i].y + v[i].z + v[i].w;
        sq += v[i].x*v[i].x + v[i].y*v[i].y + v[i].z*v[i].z + v[i].w*v[i].w;
    }
    #pragma unroll
    for (int o = 1; o < 64; o <<= 1) { s += __shfl_xor(s, o); sq += __shfl_xor(sq, o); }
    float mean = s * (1.f/768.f);
    float var  = sq * (1.f/768.f) - mean*mean;
    float rstd = rsqrtf(var + 1e-6f);
    const float4* g4 = (const float4*)g;
    const float4* b4 = (const float4*)bsh;
    #pragma unroll
    for (int i = 0; i < 3; ++i) {
        float4 gg = g4[i*64 + lane], bb = b4[i*64 + lane];
        float4 r;
        r.x = (v[i].x - mean)*rstd*gg.x + bb.x;
        r.y = (v[i].y - mean)*rstd*gg.y + bb.y;
        r.z = (v[i].z - mean)*rstd*gg.z + bb.z;
        r.w = (v[i].w - mean)*rstd*gg.w + bb.w;
        if (BF16OUT) {
            bf16x4 o4; o4[0]=(bf16_t)r.x; o4[1]=(bf16_t)r.y; o4[2]=(bf16_t)r.z; o4[3]=(bf16_t)r.w;
            ((bf16x4*)((bf16_t*)out + row * D_))[i*64 + lane] = o4;
        } else {
            ((float4*)out)[row * (D_/4) + i*64 + lane] = r;
        }
    }
}

// ---------------- GEMM 128x128, BK=64, 4 waves, dbuf LDS (64KB -> 2 blocks/CU) ----------
// C[M,N] = A[M,K] * BT[N,K]^T + bias.  Counted vmcnt prefetch depth 1, T2 swizzle,
// 2 barriers/tile.  EPI: 0 = bias->bf16 ; 1 = bias+gelu->bf16 ; 2 = bias+resid->f32
template<int EPI>
__global__ __launch_bounds__(256, 2) void k_gemm128(
        const bf16_t* __restrict__ A, const bf16_t* __restrict__ BT,
        const float* __restrict__ bias, const float* __restrict__ resid,
        void* __restrict__ Cout, int K, int N, int NB) {
    __shared__ bf16_t As[2][128 * 64];
    __shared__ bf16_t Bs[2][128 * 64];

    const int tid = threadIdx.x, lane = tid & 63, wid = tid >> 6;
    const int g = lane >> 4, fr = lane & 15, e = lane & 7;
    const int wm = (wid >> 1) * 64, wn = (wid & 1) * 64;

    // bijective XCD swizzle (m204); by = wg % NB fastest (N-neighbors share A-panel in L2)
    int nwg = (int)gridDim.x, orig = (int)blockIdx.x;
    int qq = nwg >> 3, rr = nwg & 7;
    int xcd = orig & 7, idx = orig >> 3;
    int wg = (xcd < rr ? xcd * (qq + 1) : rr * (qq + 1) + (xcd - rr) * qq) + idx;
    int bx = wg / NB, by = wg - bx * NB;
    const int gm0 = bx * 128, gn0 = by * 128;

    // staging: wave stages 32 rows of A and 32 rows of B (4+4 gload_lds, 16B each).
    // T2 swizzle: LDS chunk b of row r holds global chunk b^(r&7)  (pre-swizzled source).
    const int srl = lane >> 3, sb = lane & 7;
    const int sc = (sb ^ srl) * 8;

    f32x4 acc[4][4];
    #pragma unroll
    for (int i = 0; i < 4; ++i)
        #pragma unroll
        for (int j = 0; j < 4; ++j) acc[i][j] = (f32x4){0.f, 0.f, 0.f, 0.f};

    const bf16_t* a_src = A  + (size_t)(gm0 + wid * 32 + srl) * K + sc;
    const bf16_t* b_src = BT + (size_t)(gn0 + wid * 32 + srl) * K + sc;

    auto stage = [&](int t, int p) {
        const int k0 = t * 64;
        #pragma unroll
        for (int i = 0; i < 4; ++i) {
            __builtin_amdgcn_global_load_lds(GPTR(a_src + (size_t)(i * 8) * K + k0),
                                             LPTR(&As[p][(wid * 32 + i * 8) * 64]), 16, 0, 0);
            __builtin_amdgcn_global_load_lds(GPTR(b_src + (size_t)(i * 8) * K + k0),
                                             LPTR(&Bs[p][(wid * 32 + i * 8) * 64]), 16, 0, 0);
        }
    };

    const int NT = K >> 6;
    stage(0, 0);
    stage(1, 1);
    waitvm<8>();                      // own tile-0 loads done (<=8 left = tile 1)
    __builtin_amdgcn_s_barrier();     // everyone's tile 0 resident

    for (int t = 0; t < NT; ++t) {
        const int p = t & 1;
        bf16x8 afr[4][2], bfr[4][2];
        #pragma unroll
        for (int mi = 0; mi < 4; ++mi)
            #pragma unroll
            for (int kc = 0; kc < 2; ++kc)
                afr[mi][kc] = *(const bf16x8*)&As[p][(wm + mi*16 + fr) * 64 + (((kc*4 + g) ^ e) * 8)];
        #pragma unroll
        for (int ni = 0; ni < 4; ++ni)
            #pragma unroll
            for (int kc = 0; kc < 2; ++kc)
                bfr[ni][kc] = *(const bf16x8*)&Bs[p][(wn + ni*16 + fr) * 64 + (((kc*4 + g) ^ e) * 8)];
        asm volatile("s_waitcnt lgkmcnt(0)" ::: "memory");
        __builtin_amdgcn_sched_barrier(0);
        __builtin_amdgcn_s_barrier();          // all waves done reading buf p -> p dead
        if (t + 2 < NT) stage(t + 2, p);       // overwrite p with tile t+2
        __builtin_amdgcn_sched_barrier(0);
        __builtin_amdgcn_s_setprio(1);
        #pragma unroll
        for (int kc = 0; kc < 2; ++kc)
            #pragma unroll
            for (int mi = 0; mi < 4; ++mi)
                #pragma unroll
                for (int ni = 0; ni < 4; ++ni)
                    acc[mi][ni] = __builtin_amdgcn_mfma_f32_16x16x32_bf16(
                        afr[mi][kc], bfr[ni][kc], acc[mi][ni], 0, 0, 0);
        __builtin_amdgcn_s_setprio(0);
        if (t + 2 < NT) waitvm<8>(); else waitvm<0>();   // tile t+1 resident (own share)
        __builtin_amdgcn_s_barrier();                    // everyone's share resident
    }

    const int crow = gm0 + wm + g * 4;
    const int ccol = gn0 + wn + fr;
    #pragma unroll
    for (int mi = 0; mi < 4; ++mi)
        #pragma unroll
        for (int ni = 0; ni < 4; ++ni) {
            const int c = ccol + ni * 16;
            const float bval = bias[c];
            #pragma unroll
            for (int v = 0; v < 4; ++v) {
                const int rw = crow + mi * 16 + v;
                if (rw < M_) {
                    float val = acc[mi][ni][v] + bval;
                    if (EPI == 1) val = gelu_f(val);
                    if (EPI == 2) {
                        ((float*)Cout)[(size_t)rw * N + c] = val + resid[(size_t)rw * N + c];
                    } else {
                        ((bf16_t*)Cout)[(size_t)rw * N + c] = (bf16_t)val;
                    }
                }
            }
        }
}

// ---------------- Attention: one block per (b,h), full-row softmax ----------------
__global__ __launch_bounds__(256) void k_attn(const bf16_t* __restrict__ qkv,
                                              bf16_t* __restrict__ out) {
    __shared__ bf16_t VT[64][232];
    __shared__ bf16_t P[4][16][232];
    int tid = threadIdx.x, lane = tid & 63, wid = tid >> 6;
    int b = blockIdx.x / H_, hh = blockIdx.x % H_;
    const size_t base = (size_t)b * L_ * 2304 + hh * 64;

    for (int r = tid >> 3; r < L_; r += 32) {
        int cg = (tid & 7) * 8;
        bf16x8 vv = *(const bf16x8*)(qkv + base + (size_t)r * 2304 + 1536 + cg);
        #pragma unroll
        for (int j = 0; j < 8; ++j) VT[cg + j][r] = vv[j];
    }
    for (int i = tid; i < 64 * 35; i += 256) VT[i / 35][197 + i % 35] = (bf16_t)0.f;
    {
        int r = lane & 15, c0 = 208 + (lane >> 4) * 4;
        #pragma unroll
        for (int j = 0; j < 4; ++j) P[wid][r][c0 + j] = (bf16_t)0.f;
    }
    __syncthreads();

    for (int s = wid; s < 13; s += 4) {
        int q0 = s * 16;
        int qr = q0 + (lane & 15); if (qr > L_ - 1) qr = L_ - 1;
        bf16x8 qf[2];
        #pragma unroll
        for (int kk = 0; kk < 2; ++kk)
            qf[kk] = *(const bf16x8*)(qkv + base + (size_t)qr * 2304 + kk * 32 + (lane >> 4) * 8);

        f32x4 sacc[13];
        #pragma unroll
        for (int nb = 0; nb < 13; ++nb) { f32x4 z = {0.f,0.f,0.f,0.f}; sacc[nb] = z; }
        #pragma unroll
        for (int nb = 0; nb < 13; ++nb) {
            int lk = nb * 16 + (lane & 15); if (lk > L_ - 1) lk = L_ - 1;
            #pragma unroll
            for (int kk = 0; kk < 2; ++kk) {
                bf16x8 kf = *(const bf16x8*)(qkv + base + (size_t)lk * 2304 + D_ + kk * 32 + (lane >> 4) * 8);
                sacc[nb] = __builtin_amdgcn_mfma_f32_16x16x32_bf16(qf[kk], kf, sacc[nb], 0, 0, 0);
            }
        }

        float mx[4] = {-1e30f, -1e30f, -1e30f, -1e30f};
        float pv[13][4];
        #pragma unroll
        for (int nb = 0; nb < 13; ++nb) {
            bool valid = (nb * 16 + (lane & 15)) < L_;
            #pragma unroll
            for (int v = 0; v < 4; ++v) {
                float sv = valid ? sacc[nb][v] * 0.125f : -1e30f;
                pv[nb][v] = sv;
                mx[v] = fmaxf(mx[v], sv);
            }
        }
        #pragma unroll
        for (int o = 1; o < 16; o <<= 1) {
            #pragma unroll
            for (int v = 0; v < 4; ++v) mx[v] = fmaxf(mx[v], __shfl_xor(mx[v], o));
        }
        float sum[4] = {0.f, 0.f, 0.f, 0.f};
        #pragma unroll
        for (int nb = 0; nb < 13; ++nb) {
            bool valid = (nb * 16 + (lane & 15)) < L_;
            #pragma unroll
            for (int v = 0; v < 4; ++v) {
                float e2 = valid ? __expf(pv[nb][v] - mx[v]) : 0.f;
                pv[nb][v] = e2; sum[v] += e2;
            }
        }
        #pragma unroll
        for (int o = 1; o < 16; o <<= 1) {
            #pragma unroll
            for (int v = 0; v < 4; ++v) sum[v] += __shfl_xor(sum[v], o);
        }

        #pragma unroll
        for (int nb = 0; nb < 13; ++nb)
            #pragma unroll
            for (int v = 0; v < 4; ++v)
                P[wid][(lane >> 4) * 4 + v][nb * 16 + (lane & 15)] = (bf16_t)pv[nb][v];
        asm volatile("s_waitcnt lgkmcnt(0)" ::: "memory");

        f32x4 oacc[4];
        #pragma unroll
        for (int nb = 0; nb < 4; ++nb) { f32x4 z = {0.f,0.f,0.f,0.f}; oacc[nb] = z; }
        #pragma unroll
        for (int kk = 0; kk < 7; ++kk) {
            bf16x8 pf = *(const bf16x8*)&P[wid][lane & 15][kk * 32 + (lane >> 4) * 8];
            #pragma unroll
            for (int nb = 0; nb < 4; ++nb) {
                bf16x8 vf = *(const bf16x8*)&VT[nb * 16 + (lane & 15)][kk * 32 + (lane >> 4) * 8];
                oacc[nb] = __builtin_amdgcn_mfma_f32_16x16x32_bf16(pf, vf, oacc[nb], 0, 0, 0);
            }
        }

        float rs[4];
        #pragma unroll
        for (int v = 0; v < 4; ++v) rs[v] = 1.f / sum[v];
        #pragma unroll
        for (int nb = 0; nb < 4; ++nb)
            #pragma unroll
            for (int v = 0; v < 4; ++v) {
                int r = q0 + (lane >> 4) * 4 + v;
                if (r < L_)
                    out[((size_t)b * L_ + r) * D_ + hh * 64 + nb * 16 + (lane & 15)] =
                        (bf16_t)(oacc[nb][v] * rs[v]);
            }
    }
}

// ---------------- host orchestration ----------------
extern "C" void kernel_launch(void* const* d_in, const int* in_sizes, int n_in,
                              void* d_out, int out_size, void* d_ws, size_t ws_size,
                              hipStream_t stream) {
    const float* x     = (const float*)d_in[0];
    const float* pos   = (const float*)d_in[1];
    const float* ln1_g = (const float*)d_in[2];
    const float* ln1_b = (const float*)d_in[3];
    const float* Wq    = (const float*)d_in[4];
    const float* bq    = (const float*)d_in[5];
    const float* Wk    = (const float*)d_in[6];
    const float* bk    = (const float*)d_in[7];
    const float* Wv    = (const float*)d_in[8];
    const float* bv    = (const float*)d_in[9];
    const float* Wo    = (const float*)d_in[10];
    const float* bo    = (const float*)d_in[11];
    const float* ln2_g = (const float*)d_in[12];
    const float* ln2_b = (const float*)d_in[13];
    const float* W1    = (const float*)d_in[14];
    const float* b1    = (const float*)d_in[15];
    const float* W2    = (const float*)d_in[16];
    const float* b2    = (const float*)d_in[17];
    const float* lnf_g = (const float*)d_in[18];
    const float* lnf_b = (const float*)d_in[19];

    char* wsp = (char*)d_ws;
    size_t off = 0;
    auto alloc = [&](size_t bytes) -> void* {
        void* r = wsp + off;
        off += (bytes + 255) & ~(size_t)255;
        return r;
    };
    float*  h     = (float*) alloc((size_t)M_ * D_ * 4);
    bf16_t* y     = (bf16_t*)alloc((size_t)MPAD_ * D_ * 2);
    bf16_t* qkv   = (bf16_t*)alloc((size_t)M_ * 2304 * 2);
    bf16_t* attn  = (bf16_t*)alloc((size_t)MPAD_ * D_ * 2);
    bf16_t* u     = (bf16_t*)alloc((size_t)MPAD_ * F_ * 2);
    bf16_t* wqkvT = (bf16_t*)alloc((size_t)2304 * D_ * 2);
    bf16_t* woT   = (bf16_t*)alloc((size_t)D_ * D_ * 2);
    bf16_t* w1T   = (bf16_t*)alloc((size_t)F_ * D_ * 2);
    bf16_t* w2T   = (bf16_t*)alloc((size_t)D_ * F_ * 2);
    float*  bqkv  = (float*) alloc(2304 * 4);
    (void)ws_size; (void)in_sizes; (void)n_in; (void)out_size;

    {
        int n4 = M_ * D_ / 4;
        k_addpos4<<<(n4 + 255) / 256, 256, 0, stream>>>((const float4*)x, (const float4*)pos,
                                                        (float4*)h, n4, L_ * D_ / 4);
    }

    dim3 tDD (D_ / 64, D_ / 64);
    dim3 tDF (D_ / 64, F_ / 64);
    dim3 tFD (F_ / 64, D_ / 64);

    for (int l = 0; l < NL_; ++l) {
        k_convT<<<tDD, 256, 0, stream>>>(Wq + (size_t)l * D_ * D_, wqkvT,                     D_, D_);
        k_convT<<<tDD, 256, 0, stream>>>(Wk + (size_t)l * D_ * D_, wqkvT + (size_t)768 * D_,  D_, D_);
        k_convT<<<tDD, 256, 0, stream>>>(Wv + (size_t)l * D_ * D_, wqkvT + (size_t)1536 * D_, D_, D_);
        k_convT<<<tDD, 256, 0, stream>>>(Wo + (size_t)l * D_ * D_, woT, D_, D_);
        k_convT<<<tDF, 256, 0, stream>>>(W1 + (size_t)l * D_ * F_, w1T, D_, F_);
        k_convT<<<tFD, 256, 0, stream>>>(W2 + (size_t)l * F_ * D_, w2T, F_, D_);
        k_pack_qkvb<<<3, 256, 0, stream>>>(bq + l * D_, bk + l * D_, bv + l * D_, bqkv);

        k_ln<true><<<M_ / 4, 256, 0, stream>>>(h, ln1_g + l * D_, ln1_b + l * D_, y);
        k_gemm128<0><<<dim3(99 * 18), 256, 0, stream>>>(y,    wqkvT, bqkv,                nullptr, qkv, D_, 2304, 18);
        k_attn<<<B_ * H_, 256, 0, stream>>>(qkv, attn);
        k_gemm128<2><<<dim3(99 * 6),  256, 0, stream>>>(attn, woT,   bo + l * D_,         h,       h,   D_, D_,   6);
        k_ln<true><<<M_ / 4, 256, 0, stream>>>(h, ln2_g + l * D_, ln2_b + l * D_, y);
        k_gemm128<1><<<dim3(99 * 24), 256, 0, stream>>>(y,    w1T,   b1 + (size_t)l * F_, nullptr, u,   D_, F_,   24);
        k_gemm128<2><<<dim3(99 * 6),  256, 0, stream>>>(u,    w2T,   b2 + l * D_,         h,       h,   F_, D_,   6);
    }
    k_ln<false><<<M_ / 4, 256, 0, stream>>>(h, lnf_g, lnf_b, d_out);
}